// Round 12
// baseline (2881.970 us; speedup 1.0000x reference)
//
#include <hip/hip_runtime.h>
#include <hip/hip_bf16.h>
#include <initializer_list>

// CSNet on MI355X — round 12.
// r11 -> r12 (single-variable test, k_res only): pixel stride 76 -> 68 shorts
// (LDS 60.9 -> 54.4 KB) + __launch_bounds__(256,3) => 3 wg/CU, 12 waves/CU
// (+50% latency hiding for the 5 barriers + LDS->MFMA chains).
// Bank property unchanged (34 dwords == 2 mod 32: 2-way, free). Everything
// else byte-identical to r11 (1097 us; k_res 117.7 us = 73% of its 86 us
// MFMA-issue floor, HBM 15%, latency-bound at 2 wg/CU).
// If FETCH_SIZE jumps (r7 pattern), 2 wg is structurally optimal -> revert.
// Activations NHWC bf16: act[n][y][x][c=64].
// d_out: out[16*65536] | outcsy[16*16384] | initrec[16*65536]  (fp32)
// d_ws:  A[16 img] | Bt[nc img] | Wp[36864] bf16 | WcsT, WinitT f32

#define HW 65536
#define IMG 4194304        // 64*HW elems per image

typedef __attribute__((ext_vector_type(8))) short short8;
typedef __attribute__((ext_vector_type(4))) float f32x4;

__device__ __forceinline__ float bf2f(unsigned short u) {
    union { unsigned u; float f; } v; v.u = ((unsigned)u) << 16; return v.f;
}
__device__ __forceinline__ unsigned short f2bf(float f) {
    union { float f; unsigned u; } v; v.f = f;
    unsigned r = v.u + 0x7FFF + ((v.u >> 16) & 1);   // RNE
    return (unsigned short)(r >> 16);
}

// ---------------- weight transposes (one-time prep) ----------------
__global__ void k_wcsT(const float* __restrict__ Wcs, float* __restrict__ WT)
{
    int e = blockIdx.x * 256 + threadIdx.x;   // 262144
    int k = e >> 8, c = e & 255;
    WT[(long)k * 256 + c] = Wcs[(long)c * 1024 + k];
}

__global__ void k_winitT(const float* __restrict__ Wi, float* __restrict__ WT)
{
    int e = blockIdx.x * 256 + threadIdx.x;   // 262144
    int ci = e >> 10, cc = e & 1023;
    WT[e] = Wi[(long)cc * 256 + ci];
}

// ---------------- K1: CS sampling conv (r6 verbatim) ----------------
__global__ __launch_bounds__(256) void k_cs2(const float* __restrict__ x,
        const float* __restrict__ WT, float* __restrict__ outcsy)
{
    __shared__ float xs[2][1024];
    const int b = blockIdx.x;              // 512 blocks, pixels 2b, 2b+1
    const int tid = threadIdx.x;
#pragma unroll
    for (int t = 0; t < 2; ++t) {
        int p = b * 2 + t;                 // n*64 + hb*8 + wb
        int wb = p & 7, hb = (p >> 3) & 7, n = p >> 6;
#pragma unroll
        for (int i = 0; i < 4; ++i) {
            int k = tid + 256 * i;
            int ii = k >> 5, jj = k & 31;
            xs[t][k] = x[(long)n * HW + (hb * 32 + ii) * 256 + wb * 32 + jj];
        }
    }
    __syncthreads();
    float a0 = 0.f, a1 = 0.f;
    for (int k = 0; k < 1024; k += 8) {
#pragma unroll
        for (int u = 0; u < 8; ++u) {
            float wv = WT[(long)(k + u) * 256 + tid];   // lanes coalesced
            a0 += wv * xs[0][k + u];                    // LDS broadcast
            a1 += wv * xs[1][k + u];
        }
    }
#pragma unroll
    for (int t = 0; t < 2; ++t) {
        int p = b * 2 + t;
        int wb = p & 7, hb = (p >> 3) & 7, n = p >> 6;
        float a = t ? a1 : a0;
        outcsy[(long)n * 16384 + tid * 64 + hb * 8 + wb] = a;
    }
}

// ---------------- K2: 1x1 init conv + depth-to-space (r6 verbatim) ------------
__global__ __launch_bounds__(256) void k_init2(const float* __restrict__ outcsy,
        const float* __restrict__ WT, float* __restrict__ initrec)
{
    __shared__ float ys[2][256];
    __shared__ float ov[2][1024];
    const int b = blockIdx.x;              // s*8 + np
    const int np = b & 7, s = b >> 3;
    const int wb = s & 7, hb = s >> 3;
    const int tid = threadIdx.x;
#pragma unroll
    for (int i = 0; i < 2; ++i) {
        int idx = tid + 256 * i;
        int t = idx >> 8, c = idx & 255;
        ys[t][c] = outcsy[(long)(np * 2 + t) * 16384 + c * 64 + s];
    }
    __syncthreads();
#pragma unroll
    for (int q4 = 0; q4 < 4; ++q4) {
        int cc = q4 * 256 + tid;           // cc = j*32+i
        float a0 = 0.f, a1 = 0.f;
        for (int ci = 0; ci < 256; ci += 8) {
#pragma unroll
            for (int u = 0; u < 8; ++u) {
                float wv = WT[(long)(ci + u) * 1024 + cc];  // coalesced
                a0 += wv * ys[0][ci + u];
                a1 += wv * ys[1][ci + u];
            }
        }
        int i = cc & 31, j = cc >> 5;
        ov[0][i * 32 + j] = a0;
        ov[1][i * 32 + j] = a1;
    }
    __syncthreads();
#pragma unroll
    for (int t = 0; t < 2; ++t) {
        int n = np * 2 + t;
#pragma unroll
        for (int i2 = 0; i2 < 4; ++i2) {
            int p = i2 * 256 + tid;        // p = i*32+j
            int i = p >> 5, j = p & 31;
            initrec[(long)n * HW + (hb * 32 + i) * 256 + wb * 32 + j] = ov[t][p];
        }
    }
}

// ---------------- K3: first conv 1->64 + PReLU, pixel-per-thread (r6) ----------
__global__ __launch_bounds__(256) void k_first(const float* __restrict__ initrec,
        const float* __restrict__ Wf, unsigned short* __restrict__ A,
        const float* __restrict__ alpha_p)
{
    const int bid = blockIdx.x;            // n*256 + ty*16 + tx
    const int tx = bid & 15, ty = (bid >> 4) & 15, n = bid >> 8;
    const int tid = threadIdx.x;
    const int x = (tx << 4) + (tid & 15), y = (ty << 4) + (tid >> 4);
    const float* ip = initrec + (long)n * HW;

    float in[9];
#pragma unroll
    for (int ky = 0; ky < 3; ++ky)
#pragma unroll
        for (int kx = 0; kx < 3; ++kx) {
            int iy = y + ky - 1, ix = x + kx - 1;
            in[ky * 3 + kx] = ((unsigned)iy < 256u && (unsigned)ix < 256u)
                                  ? ip[iy * 256 + ix] : 0.f;
        }

    const float alpha = alpha_p[0];
    unsigned short* op = &A[(((long)n * 256 + y) * 256 + x) * 64];
#pragma unroll
    for (int c8 = 0; c8 < 8; ++c8) {
        short8 ov;
#pragma unroll
        for (int j = 0; j < 8; ++j) {
            const float* wp = &Wf[(c8 * 8 + j) * 9];   // uniform -> scalar loads
            float a = 0.f;
#pragma unroll
            for (int t = 0; t < 9; ++t) a += wp[t] * in[t];
            a = a >= 0.f ? a : alpha * a;
            ov[j] = (short)f2bf(a);
        }
        *(short8*)&op[c8 * 8] = ov;
    }
}

// ---------------- weight prep (r6 verbatim) ----------------
// Wp[cc][tap][nt][lane][j] = W[co=nt*16+(lane&15)][ci=cc*32+(lane>>4)*8+j][tap]
__global__ void k_wprep(const float* __restrict__ Wb, unsigned short* __restrict__ Wp)
{
    int e = blockIdx.x * 256 + threadIdx.x;   // 36864 total
    int cc = e / 18432, r = e % 18432;
    int tap = r / 2048, r2 = r % 2048;
    int nt = (r2 >> 9) & 3, l = (r2 >> 3) & 63, j = r2 & 7;
    int co = nt * 16 + (l & 15);
    int ci = cc * 32 + (l >> 4) * 8 + j;
    Wp[e] = f2bf(Wb[co * 576 + ci * 9 + tap]);
}

// ---------------- K4: fused residual pair ----------------
// dst = prelu(src + conv2(prelu(conv1(src)))).
// One 54.4 KB LDS region (pixel stride 68 shorts), barrier-separated roles:
//   halo: 20x20 px x 64 ch    o2b: 18x18 px x 64 ch    ob: 16x16 px XOR-swz
__global__ __launch_bounds__(256, 3) void k_res(const unsigned short* __restrict__ src,
        unsigned short* __restrict__ dst, const unsigned short* __restrict__ Wp,
        const float* __restrict__ alpha_p)
{
    __shared__ short smem[27200];   // 20*20 px * 68 shorts = 54.4 KB -> 3 wg/CU

    const int tid = threadIdx.x;
    const int bid = blockIdx.x;
    const int tx = bid & 15, ty = (bid >> 4) & 15, n = bid >> 8;  // n chunk-local
    const int x0 = tx * 16, y0 = ty * 16;
    const int w = tid >> 6, lane = tid & 63;
    const int q = lane >> 4, mm = lane & 15;
    const float alpha = alpha_p[0];
    const unsigned short* sb = src + (long)n * IMG;

    // conv1 M-tile pixel bases (clamp: duplicate lanes compute the SAME
    // pixel-323 value, so racing o2 writes are consistent — r6 trick)
    int pb1[6];
#pragma unroll
    for (int i = 0; i < 6; ++i) {
        int p = (w + 4 * i) * 16 + mm;
        p = p < 323 ? p : 323;
        pb1[i] = p + 2 * (p / 18);          // rho*20 + gam (20-grid index)
    }

    // ---- stage halo chunk 0: 20x20 px, channels 0..31 ----
#pragma unroll
    for (int i = 0; i < 7; ++i) {
        int idx = tid + 256 * i;            // 1600 chunks of 16 B
        if (idx < 1600) {
            int pix = idx >> 2, part = idx & 3;
            int row = pix / 20, col = pix - row * 20;
            int gy = y0 + row - 2, gx = x0 + col - 2;
            short8 v = {0, 0, 0, 0, 0, 0, 0, 0};
            if ((unsigned)gy < 256u && (unsigned)gx < 256u)
                v = *(const short8*)&sb[((long)gy * 256 + gx) * 64 + part * 8];
            *(short8*)&smem[pix * 68 + part * 8] = v;
        }
    }

    // ---- issue halo chunk 1 (channels 32..63) into REGISTERS, no waits ----
    short8 pre[7];
    int pofs[7];
#pragma unroll
    for (int i = 0; i < 7; ++i) {
        short8 z = {0, 0, 0, 0, 0, 0, 0, 0};
        pre[i] = z; pofs[i] = -1;
        int idx = tid + 256 * i;
        if (idx < 1600) {
            int pix = idx >> 2, part = (idx & 3) + 4;
            int row = pix / 20, col = pix - row * 20;
            int gy = y0 + row - 2, gx = x0 + col - 2;
            pofs[i] = pix * 68 + part * 8;
            if ((unsigned)gy < 256u && (unsigned)gx < 256u)
                pre[i] = *(const short8*)&sb[((long)gy * 256 + gx) * 64 + part * 8];
        }
    }

    short8 bcur[4], bnxt[4];
#pragma unroll
    for (int nt = 0; nt < 4; ++nt)
        bcur[nt] = *(const short8*)&Wp[(size_t)(nt * 512 + lane * 8)];

    const f32x4 zz = {0.f, 0.f, 0.f, 0.f};
    f32x4 acc1[6][4];
#pragma unroll
    for (int i = 0; i < 6; ++i)
#pragma unroll
        for (int nt = 0; nt < 4; ++nt) acc1[i][nt] = zz;

    __syncthreads();

    // ======== conv1 steps 0..8 (cc=0) — chunk-1 loads drain in background ====
#pragma unroll
    for (int s = 0; s < 9; ++s) {
        const int tap = s;
        const int un = s + 1;               // 9 -> step 9 frags
#pragma unroll
        for (int nt = 0; nt < 4; ++nt)
            bnxt[nt] = *(const short8*)&Wp[(size_t)(un / 9) * 18432 +
                       (size_t)(((un % 9) * 4 + nt) * 512 + lane * 8)];
        const int ky = tap / 3, kx = tap % 3;
        const int toff = (ky * 20 + kx) * 68 + q * 8;   // cc=0
#pragma unroll
        for (int i = 0; i < 5; ++i) {
            short8 af = *(const short8*)&smem[pb1[i] * 68 + toff];
#pragma unroll
            for (int nt = 0; nt < 4; ++nt)
                acc1[i][nt] = __builtin_amdgcn_mfma_f32_16x16x32_bf16(
                    af, bcur[nt], acc1[i][nt], 0, 0, 0);
        }
        if (w == 0) {                        // tile 20 only (21..23 unused)
            short8 af = *(const short8*)&smem[pb1[5] * 68 + toff];
#pragma unroll
            for (int nt = 0; nt < 4; ++nt)
                acc1[5][nt] = __builtin_amdgcn_mfma_f32_16x16x32_bf16(
                    af, bcur[nt], acc1[5][nt], 0, 0, 0);
        }
#pragma unroll
        for (int nt = 0; nt < 4; ++nt) bcur[nt] = bnxt[nt];
    }

    // ---- drain chunk-1 registers to LDS (vmcnt hidden behind steps 0..8) ----
#pragma unroll
    for (int i = 0; i < 7; ++i)
        if (pofs[i] >= 0) *(short8*)&smem[pofs[i]] = pre[i];
    __syncthreads();

    // ======== conv1 steps 9..17 (cc=1) ========
#pragma unroll
    for (int s = 9; s < 18; ++s) {
        const int tap = s - 9;
        int un = s + 1; un = un < 18 ? un : 0;   // wraps into conv2 step 0
#pragma unroll
        for (int nt = 0; nt < 4; ++nt)
            bnxt[nt] = *(const short8*)&Wp[(size_t)(un / 9) * 18432 +
                       (size_t)(((un % 9) * 4 + nt) * 512 + lane * 8)];
        const int ky = tap / 3, kx = tap % 3;
        const int toff = (ky * 20 + kx) * 68 + 32 + q * 8;   // cc=1
#pragma unroll
        for (int i = 0; i < 5; ++i) {
            short8 af = *(const short8*)&smem[pb1[i] * 68 + toff];
#pragma unroll
            for (int nt = 0; nt < 4; ++nt)
                acc1[i][nt] = __builtin_amdgcn_mfma_f32_16x16x32_bf16(
                    af, bcur[nt], acc1[i][nt], 0, 0, 0);
        }
        if (w == 0) {
            short8 af = *(const short8*)&smem[pb1[5] * 68 + toff];
#pragma unroll
            for (int nt = 0; nt < 4; ++nt)
                acc1[5][nt] = __builtin_amdgcn_mfma_f32_16x16x32_bf16(
                    af, bcur[nt], acc1[5][nt], 0, 0, 0);
        }
#pragma unroll
        for (int nt = 0; nt < 4; ++nt) bcur[nt] = bnxt[nt];
    }
    __syncthreads();   // conv1 reads done; smem becomes o2b (18x18, stride 68)

    // ======== write o2 = prelu(conv1); zero outside image ========
#pragma unroll
    for (int i = 0; i < 6; ++i) {
        int t = w + 4 * i;
        if (t < 21) {
#pragma unroll
            for (int r = 0; r < 4; ++r) {
                int p = t * 16 + q * 4 + r;      // o2 position (D row = q*4+r)
                p = p < 323 ? p : 323;
                int rho = p / 18, gam = p - 18 * rho;
                bool valid = (unsigned)(y0 - 1 + rho) < 256u &&
                             (unsigned)(x0 - 1 + gam) < 256u;
#pragma unroll
                for (int nt = 0; nt < 4; ++nt) {
                    float v = acc1[i][nt][r];
                    v = v >= 0.f ? v : alpha * v;
                    smem[p * 68 + nt * 16 + mm] = valid ? (short)f2bf(v) : (short)0;
                }
            }
        }
    }
    __syncthreads();

    // ======== conv2 from o2b (rows t = 4w+mt) ========
    f32x4 acc2[4][4];
#pragma unroll
    for (int mt = 0; mt < 4; ++mt)
#pragma unroll
        for (int nt = 0; nt < 4; ++nt) acc2[mt][nt] = zz;

#pragma unroll
    for (int s = 0; s < 18; ++s) {
        const int cc = s / 9, tap = s % 9;
        int un = s + 1; un = un < 18 ? un : 17;
#pragma unroll
        for (int nt = 0; nt < 4; ++nt)
            bnxt[nt] = *(const short8*)&Wp[(size_t)(un / 9) * 18432 +
                       (size_t)(((un % 9) * 4 + nt) * 512 + lane * 8)];
        const int ky = tap / 3, kx = tap % 3;
#pragma unroll
        for (int mt = 0; mt < 4; ++mt) {
            int pix = (4 * w + mt + ky) * 18 + mm + kx;
            short8 af = *(const short8*)&smem[pix * 68 + cc * 32 + q * 8];
#pragma unroll
            for (int nt = 0; nt < 4; ++nt)
                acc2[mt][nt] = __builtin_amdgcn_mfma_f32_16x16x32_bf16(
                    af, bcur[nt], acc2[mt][nt], 0, 0, 0);
        }
#pragma unroll
        for (int nt = 0; nt < 4; ++nt) bcur[nt] = bnxt[nt];
    }
    __syncthreads();   // conv2 reads done; smem becomes ob

    // ======== epilogue: XOR-swizzled stage, res-add + prelu, b128 stores ======
    unsigned short* ob = (unsigned short*)smem;      // 16384 shorts
#pragma unroll
    for (int mt = 0; mt < 4; ++mt) {
        int row = 4 * w + mt;
#pragma unroll
        for (int r = 0; r < 4; ++r) {
            int px = row * 16 + q * 4 + r;           // D row = q*4 + r = x pos
            int h = (px >> 2) & 7;
#pragma unroll
            for (int nt = 0; nt < 4; ++nt) {
                int sg = nt * 2 + (mm >> 3);         // co group (co = nt*16+mm)
                int swz = ((sg ^ h) << 3) | (mm & 7);
                ob[px * 64 + swz] = f2bf(acc2[mt][nt][r]);
            }
        }
    }
    __syncthreads();
#pragma unroll
    for (int i = 0; i < 8; ++i) {
        int c = tid + 256 * i;                       // 2048 chunks of 8 shorts
        int px = c >> 3, k = c & 7;
        int row = px >> 4, xx = px & 15;
        int h = (px >> 2) & 7;
        int co = (k ^ h) << 3;                       // un-swizzle channel group
        long g = (((long)n * 256 + y0 + row) * 256 + (x0 + xx)) * 64 + co;
        short8 cv = *(short8*)&ob[px * 64 + k * 8];
        short8 rv = *(const short8*)&src[g];
        short8 ov;
#pragma unroll
        for (int j = 0; j < 8; ++j) {
            float v = bf2f((unsigned short)cv[j]) + bf2f((unsigned short)rv[j]);
            v = (v >= 0.f) ? v : alpha * v;
            ov[j] = (short)f2bf(v);
        }
        *(short8*)&dst[g] = ov;
    }
}

// ---------------- K5: last conv (A + initrec) -> 1 channel (r6) ----------------
__global__ __launch_bounds__(256) void k_last(const unsigned short* __restrict__ A,
        const float* __restrict__ initrec, const float* __restrict__ Wl,
        float* __restrict__ out0)
{
    __shared__ short ibuf[23328];        // 18*18 px * 72-short stride
    const int bid = blockIdx.x;          // n*256 + ty*16 + tx
    const int tx = bid & 15, ty = (bid >> 4) & 15, n = bid >> 8;
    const int x0 = tx * 16, y0 = ty * 16;
    const int tid = threadIdx.x;
    const unsigned short* Ab = A + (long)n * IMG;

#pragma unroll
    for (int i = 0; i < 11; ++i) {
        int idx = tid + 256 * i;         // 2592 chunks
        if (idx < 2592) {
            int pix = idx >> 3, part = idx & 7;
            int row = pix / 18, col = pix - row * 18;
            int gy = y0 + row - 1, gx = x0 + col - 1;
            short8 v = {0, 0, 0, 0, 0, 0, 0, 0};
            if ((unsigned)gy < 256u && (unsigned)gx < 256u)
                v = *(const short8*)&Ab[((long)gy * 256 + gx) * 64 + part * 8];
            *(short8*)&ibuf[pix * 72 + part * 8] = v;
        }
    }
    __syncthreads();

    float wsum[9];
#pragma unroll
    for (int k = 0; k < 9; ++k) wsum[k] = 0.f;
    for (int ci = 0; ci < 64; ++ci)
#pragma unroll
        for (int k = 0; k < 9; ++k) wsum[k] += Wl[ci * 9 + k];

    const int x = tid & 15, y = tid >> 4;
    const float* ip = initrec + (long)n * HW;
    float acc = 0.f;
#pragma unroll
    for (int ky = 0; ky < 3; ++ky) {
#pragma unroll
        for (int kx = 0; kx < 3; ++kx) {
            const int tap = ky * 3 + kx;
            const short* p = &ibuf[((y + ky) * 18 + (x + kx)) * 72];
#pragma unroll
            for (int c8 = 0; c8 < 8; ++c8) {
                short8 av = *(const short8*)&p[c8 * 8];
#pragma unroll
                for (int j = 0; j < 8; ++j)
                    acc += Wl[(c8 * 8 + j) * 9 + tap] * bf2f((unsigned short)av[j]);
            }
            int gy = y0 + y + ky - 1, gx = x0 + x + kx - 1;
            if ((unsigned)gy < 256u && (unsigned)gx < 256u)
                acc += wsum[tap] * ip[gy * 256 + gx];
        }
    }
    out0[((long)n * 256 + y0 + y) * 256 + (x0 + x)] = acc;
}

extern "C" void kernel_launch(void* const* d_in, const int* in_sizes, int n_in,
                              void* d_out, int out_size, void* d_ws, size_t ws_size,
                              hipStream_t stream)
{
    const float* x     = (const float*)d_in[0];
    const float* Wcs   = (const float*)d_in[1];
    const float* Winit = (const float*)d_in[2];
    const float* Wf    = (const float*)d_in[3];
    const float* Wb    = (const float*)d_in[4];
    const float* Wl    = (const float*)d_in[5];
    const float* amain = (const float*)d_in[6];
    const float* ablk  = (const float*)d_in[7];

    float* out0    = (float*)d_out;
    float* outcsy  = out0 + 1048576;
    float* initrec = outcsy + 262144;

    const size_t EXTRA = 73728 + 2 * 1048576;         // Wp + WcsT + WinitT bytes
    unsigned short* A = (unsigned short*)d_ws;        // [16] img bf16 NHWC
    int nc = 1;
    for (int c : {16, 8, 4, 2, 1})
        if ((size_t)(16 + c) * IMG * 2 + EXTRA <= ws_size) { nc = c; break; }
    unsigned short* Bt   = A + (size_t)16 * IMG;      // [nc] img temp
    unsigned short* Wp   = Bt + (size_t)nc * IMG;     // 36864 bf16
    float*          WcsT = (float*)(Wp + 36864);      // 262144 f32
    float*          WinT = WcsT + 262144;             // 262144 f32

    k_wcsT<<<1024, 256, 0, stream>>>(Wcs, WcsT);
    k_winitT<<<1024, 256, 0, stream>>>(Winit, WinT);
    k_wprep<<<144, 256, 0, stream>>>(Wb, Wp);

    k_cs2<<<512, 256, 0, stream>>>(x, WcsT, outcsy);
    k_init2<<<512, 256, 0, stream>>>(outcsy, WinT, initrec);
    k_first<<<4096, 256, 0, stream>>>(initrec, Wf, A, amain);

    // 4 residual iterations; per image-chunk, ping-pong A <-> Bt (even count
    // of iterations leaves the result back in A).
    for (int n0 = 0; n0 < 16; n0 += nc) {
        unsigned short* Ac = A + (size_t)n0 * IMG;
        for (int i = 0; i < 4; ++i) {
            const unsigned short* s = (i & 1) ? Bt : Ac;
            unsigned short*       d = (i & 1) ? Ac : Bt;
            k_res<<<nc * 256, 256, 0, stream>>>(s, d, Wp, ablk);
        }
    }
    k_last<<<4096, 256, 0, stream>>>(A, initrec, Wl, out0);
}

// Round 13
// 1092.916 us; speedup vs baseline: 2.6370x; 2.6370x over previous
//
#include <hip/hip_runtime.h>
#include <hip/hip_bf16.h>
#include <initializer_list>

// CSNet on MI355X — round 13: byte-for-byte revert to r11 (best measured,
// 1097 us). r12's __launch_bounds__(256,3) caused VGPR 128->84 + accumulator
// spill-to-scratch (WRITE_SIZE 78->473 MB, dur 118->345 us), and 3 wg never
// fit anyway (LDS 512-B granule: 3*54784 B > 160 KiB). The 16x16-tile fused
// k_res is structurally locked at 2 wg/CU; r11 is its measured optimum:
// 117.7 us/dispatch = 73% of the 86 us MFMA-issue floor, remainder = barrier
// latency at 8 waves/CU. Occupancy family (r7/r8/r12) and conflict-swizzle
// family (r7/r8/r11-partial) both explored to exhaustion.
// Activations NHWC bf16: act[n][y][x][c=64].
// d_out: out[16*65536] | outcsy[16*16384] | initrec[16*65536]  (fp32)
// d_ws:  A[16 img] | Bt[nc img] | Wp[36864] bf16 | WcsT, WinitT f32

#define HW 65536
#define IMG 4194304        // 64*HW elems per image

typedef __attribute__((ext_vector_type(8))) short short8;
typedef __attribute__((ext_vector_type(4))) float f32x4;

__device__ __forceinline__ float bf2f(unsigned short u) {
    union { unsigned u; float f; } v; v.u = ((unsigned)u) << 16; return v.f;
}
__device__ __forceinline__ unsigned short f2bf(float f) {
    union { float f; unsigned u; } v; v.f = f;
    unsigned r = v.u + 0x7FFF + ((v.u >> 16) & 1);   // RNE
    return (unsigned short)(r >> 16);
}

// ---------------- weight transposes (one-time prep) ----------------
__global__ void k_wcsT(const float* __restrict__ Wcs, float* __restrict__ WT)
{
    int e = blockIdx.x * 256 + threadIdx.x;   // 262144
    int k = e >> 8, c = e & 255;
    WT[(long)k * 256 + c] = Wcs[(long)c * 1024 + k];
}

__global__ void k_winitT(const float* __restrict__ Wi, float* __restrict__ WT)
{
    int e = blockIdx.x * 256 + threadIdx.x;   // 262144
    int ci = e >> 10, cc = e & 1023;
    WT[e] = Wi[(long)cc * 256 + ci];
}

// ---------------- K1: CS sampling conv (r6 verbatim) ----------------
__global__ __launch_bounds__(256) void k_cs2(const float* __restrict__ x,
        const float* __restrict__ WT, float* __restrict__ outcsy)
{
    __shared__ float xs[2][1024];
    const int b = blockIdx.x;              // 512 blocks, pixels 2b, 2b+1
    const int tid = threadIdx.x;
#pragma unroll
    for (int t = 0; t < 2; ++t) {
        int p = b * 2 + t;                 // n*64 + hb*8 + wb
        int wb = p & 7, hb = (p >> 3) & 7, n = p >> 6;
#pragma unroll
        for (int i = 0; i < 4; ++i) {
            int k = tid + 256 * i;
            int ii = k >> 5, jj = k & 31;
            xs[t][k] = x[(long)n * HW + (hb * 32 + ii) * 256 + wb * 32 + jj];
        }
    }
    __syncthreads();
    float a0 = 0.f, a1 = 0.f;
    for (int k = 0; k < 1024; k += 8) {
#pragma unroll
        for (int u = 0; u < 8; ++u) {
            float wv = WT[(long)(k + u) * 256 + tid];   // lanes coalesced
            a0 += wv * xs[0][k + u];                    // LDS broadcast
            a1 += wv * xs[1][k + u];
        }
    }
#pragma unroll
    for (int t = 0; t < 2; ++t) {
        int p = b * 2 + t;
        int wb = p & 7, hb = (p >> 3) & 7, n = p >> 6;
        float a = t ? a1 : a0;
        outcsy[(long)n * 16384 + tid * 64 + hb * 8 + wb] = a;
    }
}

// ---------------- K2: 1x1 init conv + depth-to-space (r6 verbatim) ------------
__global__ __launch_bounds__(256) void k_init2(const float* __restrict__ outcsy,
        const float* __restrict__ WT, float* __restrict__ initrec)
{
    __shared__ float ys[2][256];
    __shared__ float ov[2][1024];
    const int b = blockIdx.x;              // s*8 + np
    const int np = b & 7, s = b >> 3;
    const int wb = s & 7, hb = s >> 3;
    const int tid = threadIdx.x;
#pragma unroll
    for (int i = 0; i < 2; ++i) {
        int idx = tid + 256 * i;
        int t = idx >> 8, c = idx & 255;
        ys[t][c] = outcsy[(long)(np * 2 + t) * 16384 + c * 64 + s];
    }
    __syncthreads();
#pragma unroll
    for (int q4 = 0; q4 < 4; ++q4) {
        int cc = q4 * 256 + tid;           // cc = j*32+i
        float a0 = 0.f, a1 = 0.f;
        for (int ci = 0; ci < 256; ci += 8) {
#pragma unroll
            for (int u = 0; u < 8; ++u) {
                float wv = WT[(long)(ci + u) * 1024 + cc];  // coalesced
                a0 += wv * ys[0][ci + u];
                a1 += wv * ys[1][ci + u];
            }
        }
        int i = cc & 31, j = cc >> 5;
        ov[0][i * 32 + j] = a0;
        ov[1][i * 32 + j] = a1;
    }
    __syncthreads();
#pragma unroll
    for (int t = 0; t < 2; ++t) {
        int n = np * 2 + t;
#pragma unroll
        for (int i2 = 0; i2 < 4; ++i2) {
            int p = i2 * 256 + tid;        // p = i*32+j
            int i = p >> 5, j = p & 31;
            initrec[(long)n * HW + (hb * 32 + i) * 256 + wb * 32 + j] = ov[t][p];
        }
    }
}

// ---------------- K3: first conv 1->64 + PReLU, pixel-per-thread (r6) ----------
__global__ __launch_bounds__(256) void k_first(const float* __restrict__ initrec,
        const float* __restrict__ Wf, unsigned short* __restrict__ A,
        const float* __restrict__ alpha_p)
{
    const int bid = blockIdx.x;            // n*256 + ty*16 + tx
    const int tx = bid & 15, ty = (bid >> 4) & 15, n = bid >> 8;
    const int tid = threadIdx.x;
    const int x = (tx << 4) + (tid & 15), y = (ty << 4) + (tid >> 4);
    const float* ip = initrec + (long)n * HW;

    float in[9];
#pragma unroll
    for (int ky = 0; ky < 3; ++ky)
#pragma unroll
        for (int kx = 0; kx < 3; ++kx) {
            int iy = y + ky - 1, ix = x + kx - 1;
            in[ky * 3 + kx] = ((unsigned)iy < 256u && (unsigned)ix < 256u)
                                  ? ip[iy * 256 + ix] : 0.f;
        }

    const float alpha = alpha_p[0];
    unsigned short* op = &A[(((long)n * 256 + y) * 256 + x) * 64];
#pragma unroll
    for (int c8 = 0; c8 < 8; ++c8) {
        short8 ov;
#pragma unroll
        for (int j = 0; j < 8; ++j) {
            const float* wp = &Wf[(c8 * 8 + j) * 9];   // uniform -> scalar loads
            float a = 0.f;
#pragma unroll
            for (int t = 0; t < 9; ++t) a += wp[t] * in[t];
            a = a >= 0.f ? a : alpha * a;
            ov[j] = (short)f2bf(a);
        }
        *(short8*)&op[c8 * 8] = ov;
    }
}

// ---------------- weight prep (r6 verbatim) ----------------
// Wp[cc][tap][nt][lane][j] = W[co=nt*16+(lane&15)][ci=cc*32+(lane>>4)*8+j][tap]
__global__ void k_wprep(const float* __restrict__ Wb, unsigned short* __restrict__ Wp)
{
    int e = blockIdx.x * 256 + threadIdx.x;   // 36864 total
    int cc = e / 18432, r = e % 18432;
    int tap = r / 2048, r2 = r % 2048;
    int nt = (r2 >> 9) & 3, l = (r2 >> 3) & 63, j = r2 & 7;
    int co = nt * 16 + (l & 15);
    int ci = cc * 32 + (l >> 4) * 8 + j;
    Wp[e] = f2bf(Wb[co * 576 + ci * 9 + tap]);
}

// ---------------- K4: fused residual pair (r11 verbatim) ----------------
// dst = prelu(src + conv2(prelu(conv1(src)))).
// One 60.8 KB LDS region (pixel stride 76 shorts), barrier-separated roles:
//   halo: 20x20 px x 64 ch    o2b: 18x18 px x 64 ch    ob: 16x16 px XOR-swz
__global__ __launch_bounds__(256, 2) void k_res(const unsigned short* __restrict__ src,
        unsigned short* __restrict__ dst, const unsigned short* __restrict__ Wp,
        const float* __restrict__ alpha_p)
{
    __shared__ short smem[30400];   // 20*20 px * 76 shorts = 60.8 KB

    const int tid = threadIdx.x;
    const int bid = blockIdx.x;
    const int tx = bid & 15, ty = (bid >> 4) & 15, n = bid >> 8;  // n chunk-local
    const int x0 = tx * 16, y0 = ty * 16;
    const int w = tid >> 6, lane = tid & 63;
    const int q = lane >> 4, mm = lane & 15;
    const float alpha = alpha_p[0];
    const unsigned short* sb = src + (long)n * IMG;

    // conv1 M-tile pixel bases (clamp: duplicate lanes compute the SAME
    // pixel-323 value, so racing o2 writes are consistent — r6 trick)
    int pb1[6];
#pragma unroll
    for (int i = 0; i < 6; ++i) {
        int p = (w + 4 * i) * 16 + mm;
        p = p < 323 ? p : 323;
        pb1[i] = p + 2 * (p / 18);          // rho*20 + gam (20-grid index)
    }

    // ---- stage halo chunk 0: 20x20 px, channels 0..31 ----
#pragma unroll
    for (int i = 0; i < 7; ++i) {
        int idx = tid + 256 * i;            // 1600 chunks of 16 B
        if (idx < 1600) {
            int pix = idx >> 2, part = idx & 3;
            int row = pix / 20, col = pix - row * 20;
            int gy = y0 + row - 2, gx = x0 + col - 2;
            short8 v = {0, 0, 0, 0, 0, 0, 0, 0};
            if ((unsigned)gy < 256u && (unsigned)gx < 256u)
                v = *(const short8*)&sb[((long)gy * 256 + gx) * 64 + part * 8];
            *(short8*)&smem[pix * 76 + part * 8] = v;
        }
    }

    // ---- issue halo chunk 1 (channels 32..63) into REGISTERS, no waits ----
    short8 pre[7];
    int pofs[7];
#pragma unroll
    for (int i = 0; i < 7; ++i) {
        short8 z = {0, 0, 0, 0, 0, 0, 0, 0};
        pre[i] = z; pofs[i] = -1;
        int idx = tid + 256 * i;
        if (idx < 1600) {
            int pix = idx >> 2, part = (idx & 3) + 4;
            int row = pix / 20, col = pix - row * 20;
            int gy = y0 + row - 2, gx = x0 + col - 2;
            pofs[i] = pix * 76 + part * 8;
            if ((unsigned)gy < 256u && (unsigned)gx < 256u)
                pre[i] = *(const short8*)&sb[((long)gy * 256 + gx) * 64 + part * 8];
        }
    }

    short8 bcur[4], bnxt[4];
#pragma unroll
    for (int nt = 0; nt < 4; ++nt)
        bcur[nt] = *(const short8*)&Wp[(size_t)(nt * 512 + lane * 8)];

    const f32x4 zz = {0.f, 0.f, 0.f, 0.f};
    f32x4 acc1[6][4];
#pragma unroll
    for (int i = 0; i < 6; ++i)
#pragma unroll
        for (int nt = 0; nt < 4; ++nt) acc1[i][nt] = zz;

    __syncthreads();

    // ======== conv1 steps 0..8 (cc=0) — chunk-1 loads drain in background ====
#pragma unroll
    for (int s = 0; s < 9; ++s) {
        const int tap = s;
        const int un = s + 1;               // 9 -> step 9 frags
#pragma unroll
        for (int nt = 0; nt < 4; ++nt)
            bnxt[nt] = *(const short8*)&Wp[(size_t)(un / 9) * 18432 +
                       (size_t)(((un % 9) * 4 + nt) * 512 + lane * 8)];
        const int ky = tap / 3, kx = tap % 3;
        const int toff = (ky * 20 + kx) * 76 + q * 8;   // cc=0
#pragma unroll
        for (int i = 0; i < 5; ++i) {
            short8 af = *(const short8*)&smem[pb1[i] * 76 + toff];
#pragma unroll
            for (int nt = 0; nt < 4; ++nt)
                acc1[i][nt] = __builtin_amdgcn_mfma_f32_16x16x32_bf16(
                    af, bcur[nt], acc1[i][nt], 0, 0, 0);
        }
        if (w == 0) {                        // tile 20 only (21..23 unused)
            short8 af = *(const short8*)&smem[pb1[5] * 76 + toff];
#pragma unroll
            for (int nt = 0; nt < 4; ++nt)
                acc1[5][nt] = __builtin_amdgcn_mfma_f32_16x16x32_bf16(
                    af, bcur[nt], acc1[5][nt], 0, 0, 0);
        }
#pragma unroll
        for (int nt = 0; nt < 4; ++nt) bcur[nt] = bnxt[nt];
    }

    // ---- drain chunk-1 registers to LDS (vmcnt hidden behind steps 0..8) ----
#pragma unroll
    for (int i = 0; i < 7; ++i)
        if (pofs[i] >= 0) *(short8*)&smem[pofs[i]] = pre[i];
    __syncthreads();

    // ======== conv1 steps 9..17 (cc=1) ========
#pragma unroll
    for (int s = 9; s < 18; ++s) {
        const int tap = s - 9;
        int un = s + 1; un = un < 18 ? un : 0;   // wraps into conv2 step 0
#pragma unroll
        for (int nt = 0; nt < 4; ++nt)
            bnxt[nt] = *(const short8*)&Wp[(size_t)(un / 9) * 18432 +
                       (size_t)(((un % 9) * 4 + nt) * 512 + lane * 8)];
        const int ky = tap / 3, kx = tap % 3;
        const int toff = (ky * 20 + kx) * 76 + 32 + q * 8;   // cc=1
#pragma unroll
        for (int i = 0; i < 5; ++i) {
            short8 af = *(const short8*)&smem[pb1[i] * 76 + toff];
#pragma unroll
            for (int nt = 0; nt < 4; ++nt)
                acc1[i][nt] = __builtin_amdgcn_mfma_f32_16x16x32_bf16(
                    af, bcur[nt], acc1[i][nt], 0, 0, 0);
        }
        if (w == 0) {
            short8 af = *(const short8*)&smem[pb1[5] * 76 + toff];
#pragma unroll
            for (int nt = 0; nt < 4; ++nt)
                acc1[5][nt] = __builtin_amdgcn_mfma_f32_16x16x32_bf16(
                    af, bcur[nt], acc1[5][nt], 0, 0, 0);
        }
#pragma unroll
        for (int nt = 0; nt < 4; ++nt) bcur[nt] = bnxt[nt];
    }
    __syncthreads();   // conv1 reads done; smem becomes o2b (18x18, stride 76)

    // ======== write o2 = prelu(conv1); zero outside image ========
#pragma unroll
    for (int i = 0; i < 6; ++i) {
        int t = w + 4 * i;
        if (t < 21) {
#pragma unroll
            for (int r = 0; r < 4; ++r) {
                int p = t * 16 + q * 4 + r;      // o2 position (D row = q*4+r)
                p = p < 323 ? p : 323;
                int rho = p / 18, gam = p - 18 * rho;
                bool valid = (unsigned)(y0 - 1 + rho) < 256u &&
                             (unsigned)(x0 - 1 + gam) < 256u;
#pragma unroll
                for (int nt = 0; nt < 4; ++nt) {
                    float v = acc1[i][nt][r];
                    v = v >= 0.f ? v : alpha * v;
                    smem[p * 76 + nt * 16 + mm] = valid ? (short)f2bf(v) : (short)0;
                }
            }
        }
    }
    __syncthreads();

    // ======== conv2 from o2b (rows t = 4w+mt) ========
    f32x4 acc2[4][4];
#pragma unroll
    for (int mt = 0; mt < 4; ++mt)
#pragma unroll
        for (int nt = 0; nt < 4; ++nt) acc2[mt][nt] = zz;

#pragma unroll
    for (int s = 0; s < 18; ++s) {
        const int cc = s / 9, tap = s % 9;
        int un = s + 1; un = un < 18 ? un : 17;
#pragma unroll
        for (int nt = 0; nt < 4; ++nt)
            bnxt[nt] = *(const short8*)&Wp[(size_t)(un / 9) * 18432 +
                       (size_t)(((un % 9) * 4 + nt) * 512 + lane * 8)];
        const int ky = tap / 3, kx = tap % 3;
#pragma unroll
        for (int mt = 0; mt < 4; ++mt) {
            int pix = (4 * w + mt + ky) * 18 + mm + kx;
            short8 af = *(const short8*)&smem[pix * 76 + cc * 32 + q * 8];
#pragma unroll
            for (int nt = 0; nt < 4; ++nt)
                acc2[mt][nt] = __builtin_amdgcn_mfma_f32_16x16x32_bf16(
                    af, bcur[nt], acc2[mt][nt], 0, 0, 0);
        }
#pragma unroll
        for (int nt = 0; nt < 4; ++nt) bcur[nt] = bnxt[nt];
    }
    __syncthreads();   // conv2 reads done; smem becomes ob

    // ======== epilogue: XOR-swizzled stage, res-add + prelu, b128 stores ======
    unsigned short* ob = (unsigned short*)smem;      // 16384 shorts
#pragma unroll
    for (int mt = 0; mt < 4; ++mt) {
        int row = 4 * w + mt;
#pragma unroll
        for (int r = 0; r < 4; ++r) {
            int px = row * 16 + q * 4 + r;           // D row = q*4 + r = x pos
            int h = (px >> 2) & 7;
#pragma unroll
            for (int nt = 0; nt < 4; ++nt) {
                int sg = nt * 2 + (mm >> 3);         // co group (co = nt*16+mm)
                int swz = ((sg ^ h) << 3) | (mm & 7);
                ob[px * 64 + swz] = f2bf(acc2[mt][nt][r]);
            }
        }
    }
    __syncthreads();
#pragma unroll
    for (int i = 0; i < 8; ++i) {
        int c = tid + 256 * i;                       // 2048 chunks of 8 shorts
        int px = c >> 3, k = c & 7;
        int row = px >> 4, xx = px & 15;
        int h = (px >> 2) & 7;
        int co = (k ^ h) << 3;                       // un-swizzle channel group
        long g = (((long)n * 256 + y0 + row) * 256 + (x0 + xx)) * 64 + co;
        short8 cv = *(short8*)&ob[px * 64 + k * 8];
        short8 rv = *(const short8*)&src[g];
        short8 ov;
#pragma unroll
        for (int j = 0; j < 8; ++j) {
            float v = bf2f((unsigned short)cv[j]) + bf2f((unsigned short)rv[j]);
            v = (v >= 0.f) ? v : alpha * v;
            ov[j] = (short)f2bf(v);
        }
        *(short8*)&dst[g] = ov;
    }
}

// ---------------- K5: last conv (A + initrec) -> 1 channel (r6) ----------------
__global__ __launch_bounds__(256) void k_last(const unsigned short* __restrict__ A,
        const float* __restrict__ initrec, const float* __restrict__ Wl,
        float* __restrict__ out0)
{
    __shared__ short ibuf[23328];        // 18*18 px * 72-short stride
    const int bid = blockIdx.x;          // n*256 + ty*16 + tx
    const int tx = bid & 15, ty = (bid >> 4) & 15, n = bid >> 8;
    const int x0 = tx * 16, y0 = ty * 16;
    const int tid = threadIdx.x;
    const unsigned short* Ab = A + (long)n * IMG;

#pragma unroll
    for (int i = 0; i < 11; ++i) {
        int idx = tid + 256 * i;         // 2592 chunks
        if (idx < 2592) {
            int pix = idx >> 3, part = idx & 7;
            int row = pix / 18, col = pix - row * 18;
            int gy = y0 + row - 1, gx = x0 + col - 1;
            short8 v = {0, 0, 0, 0, 0, 0, 0, 0};
            if ((unsigned)gy < 256u && (unsigned)gx < 256u)
                v = *(const short8*)&Ab[((long)gy * 256 + gx) * 64 + part * 8];
            *(short8*)&ibuf[pix * 72 + part * 8] = v;
        }
    }
    __syncthreads();

    float wsum[9];
#pragma unroll
    for (int k = 0; k < 9; ++k) wsum[k] = 0.f;
    for (int ci = 0; ci < 64; ++ci)
#pragma unroll
        for (int k = 0; k < 9; ++k) wsum[k] += Wl[ci * 9 + k];

    const int x = tid & 15, y = tid >> 4;
    const float* ip = initrec + (long)n * HW;
    float acc = 0.f;
#pragma unroll
    for (int ky = 0; ky < 3; ++ky) {
#pragma unroll
        for (int kx = 0; kx < 3; ++kx) {
            const int tap = ky * 3 + kx;
            const short* p = &ibuf[((y + ky) * 18 + (x + kx)) * 72];
#pragma unroll
            for (int c8 = 0; c8 < 8; ++c8) {
                short8 av = *(const short8*)&p[c8 * 8];
#pragma unroll
                for (int j = 0; j < 8; ++j)
                    acc += Wl[(c8 * 8 + j) * 9 + tap] * bf2f((unsigned short)av[j]);
            }
            int gy = y0 + y + ky - 1, gx = x0 + x + kx - 1;
            if ((unsigned)gy < 256u && (unsigned)gx < 256u)
                acc += wsum[tap] * ip[gy * 256 + gx];
        }
    }
    out0[((long)n * 256 + y0 + y) * 256 + (x0 + x)] = acc;
}

extern "C" void kernel_launch(void* const* d_in, const int* in_sizes, int n_in,
                              void* d_out, int out_size, void* d_ws, size_t ws_size,
                              hipStream_t stream)
{
    const float* x     = (const float*)d_in[0];
    const float* Wcs   = (const float*)d_in[1];
    const float* Winit = (const float*)d_in[2];
    const float* Wf    = (const float*)d_in[3];
    const float* Wb    = (const float*)d_in[4];
    const float* Wl    = (const float*)d_in[5];
    const float* amain = (const float*)d_in[6];
    const float* ablk  = (const float*)d_in[7];

    float* out0    = (float*)d_out;
    float* outcsy  = out0 + 1048576;
    float* initrec = outcsy + 262144;

    const size_t EXTRA = 73728 + 2 * 1048576;         // Wp + WcsT + WinitT bytes
    unsigned short* A = (unsigned short*)d_ws;        // [16] img bf16 NHWC
    int nc = 1;
    for (int c : {16, 8, 4, 2, 1})
        if ((size_t)(16 + c) * IMG * 2 + EXTRA <= ws_size) { nc = c; break; }
    unsigned short* Bt   = A + (size_t)16 * IMG;      // [nc] img temp
    unsigned short* Wp   = Bt + (size_t)nc * IMG;     // 36864 bf16
    float*          WcsT = (float*)(Wp + 36864);      // 262144 f32
    float*          WinT = WcsT + 262144;             // 262144 f32

    k_wcsT<<<1024, 256, 0, stream>>>(Wcs, WcsT);
    k_winitT<<<1024, 256, 0, stream>>>(Winit, WinT);
    k_wprep<<<144, 256, 0, stream>>>(Wb, Wp);

    k_cs2<<<512, 256, 0, stream>>>(x, WcsT, outcsy);
    k_init2<<<512, 256, 0, stream>>>(outcsy, WinT, initrec);
    k_first<<<4096, 256, 0, stream>>>(initrec, Wf, A, amain);

    // 4 residual iterations; per image-chunk, ping-pong A <-> Bt (even count
    // of iterations leaves the result back in A).
    for (int n0 = 0; n0 < 16; n0 += nc) {
        unsigned short* Ac = A + (size_t)n0 * IMG;
        for (int i = 0; i < 4; ++i) {
            const unsigned short* s = (i & 1) ? Bt : Ac;
            unsigned short*       d = (i & 1) ? Ac : Bt;
            k_res<<<nc * 256, 256, 0, stream>>>(s, d, Wp, ablk);
        }
    }
    k_last<<<4096, 256, 0, stream>>>(A, initrec, Wl, out0);
}